// Round 1
// baseline (101.253 us; speedup 1.0000x reference)
//
#include <hip/hip_runtime.h>
#include <math.h>

#define TWO_N 512
#define DM    256

// One block per row i. 256 threads.
__global__ __launch_bounds__(256) void supcr_main(
    const float* __restrict__ E,      // [512, 256]
    const float* __restrict__ T,      // [512]
    double* __restrict__ block_sums)  // [512] in ws
{
    const int i = blockIdx.x;
    const int t = threadIdx.x;

    __shared__ __align__(16) float  ei[DM];        // e_i staged
    __shared__ float2 dspack[TWO_N];               // {d[i,j], s_masked[i,j]}
    __shared__ float  r_row[TWO_N];                // r[i,j]
    __shared__ double red[256];

    // stage e_i (one element per thread; DM == blockDim.x)
    ei[t] = E[i * DM + t];
    __syncthreads();

    const float ti = T[i];

    // phase 1: distances for j = t and j = t + 256
    for (int j = t; j < TWO_N; j += 256) {
        const float4* ej4 = reinterpret_cast<const float4*>(E + j * DM);
        const float4* ei4 = reinterpret_cast<const float4*>(ei);
        float acc = 0.f;
        #pragma unroll 8
        for (int d4 = 0; d4 < DM / 4; ++d4) {
            float4 a = ei4[d4];   // LDS broadcast
            float4 b = ej4[d4];   // global, L2-resident
            float dx = a.x - b.x, dy = a.y - b.y, dz = a.z - b.z, dw = a.w - b.w;
            acc += dx * dx;
            acc += dy * dy;
            acc += dz * dz;
            acc += dw * dw;
        }
        float r = sqrtf(acc);
        r_row[j] = r;
        float s = (j == i) ? 0.f : __expf(-r);     // s~[i,i]=0 implements j!=i mask
        dspack[j] = make_float2(fabsf(ti - T[j]), s);
    }
    __syncthreads();

    // phase 2: per-k masked denominator + loss term
    float local = 0.f;   // sum over this thread's k of (log s - log denom)
    for (int k = t; k < TWO_N; k += 256) {
        if (k == i) continue;
        const float th = dspack[k].x;
        float denom = 0.f;
        #pragma unroll 8
        for (int j = 0; j < TWO_N; ++j) {
            float2 p = dspack[j];                  // LDS broadcast (wave-uniform j)
            denom += (p.x >= th) ? p.y : 0.f;      // includes j==k; j==i has s=0
        }
        local += -r_row[k] - logf(denom);
    }

    // phase 3: block reduction in double
    red[t] = (double)local;
    __syncthreads();
    for (int off = 128; off > 0; off >>= 1) {
        if (t < off) red[t] += red[t + off];
        __syncthreads();
    }
    if (t == 0) block_sums[i] = red[0];
}

__global__ __launch_bounds__(TWO_N) void supcr_finalize(
    const double* __restrict__ block_sums, float* __restrict__ out)
{
    __shared__ double red[TWO_N];
    const int t = threadIdx.x;
    red[t] = block_sums[t];
    __syncthreads();
    for (int off = TWO_N / 2; off > 0; off >>= 1) {
        if (t < off) red[t] += red[t + off];
        __syncthreads();
    }
    if (t == 0)
        out[0] = (float)(-red[0] / (double)((long long)TWO_N * (TWO_N - 1)));
}

extern "C" void kernel_launch(void* const* d_in, const int* in_sizes, int n_in,
                              void* d_out, int out_size, void* d_ws, size_t ws_size,
                              hipStream_t stream) {
    (void)in_sizes; (void)n_in; (void)out_size; (void)ws_size;
    const float* E = (const float*)d_in[0];   // embeddings [512,256] fp32
    const float* T = (const float*)d_in[1];   // targets    [512]     fp32
    float* out = (float*)d_out;
    double* block_sums = (double*)d_ws;       // 512 doubles = 4 KB of ws

    supcr_main<<<TWO_N, 256, 0, stream>>>(E, T, block_sums);
    supcr_finalize<<<1, TWO_N, 0, stream>>>(block_sums, out);
}

// Round 2
// 100.686 us; speedup vs baseline: 1.0056x; 1.0056x over previous
//
#include <hip/hip_runtime.h>
#include <math.h>

#define TWO_N 512
#define DM    256
#define NT    256

// One block per row i. 256 threads, each owns elements {t, t+256}.
__global__ __launch_bounds__(NT) void supcr_main(
    const float* __restrict__ E,      // [512, 256]
    const float* __restrict__ T,      // [512]
    double* __restrict__ block_sums)  // [512] in ws
{
    const int i = blockIdx.x;
    const int t = threadIdx.x;

    __shared__ __align__(16) float  ei[DM];    // e_i staged
    __shared__ float2 ds[TWO_N];               // {d[i,j], s_masked[i,j]} original order
    __shared__ float  r_row[TWO_N];            // r[i,j]
    __shared__ float2 sd[TWO_N];               // sorted-by-d copy
    __shared__ float  suf[TWO_N];              // inclusive suffix sums of sorted s
    __shared__ double red[NT];

    ei[t] = E[i * DM + t];
    __syncthreads();

    const float ti = T[i];

    // ---- phase 1: distances for j0 = t, j1 = t+256 (interleaved for MLP) ----
    {
        const float4* __restrict__ ei4 = reinterpret_cast<const float4*>(ei);
        const float4* __restrict__ b0  = reinterpret_cast<const float4*>(E + (size_t)t * DM);
        const float4* __restrict__ b1  = reinterpret_cast<const float4*>(E + (size_t)(t + 256) * DM);
        float4 a0 = make_float4(0.f, 0.f, 0.f, 0.f);
        float4 a1 = make_float4(0.f, 0.f, 0.f, 0.f);
        #pragma unroll 8
        for (int d4 = 0; d4 < DM / 4; ++d4) {
            const float4 a = ei4[d4];
            const float4 p = b0[d4];
            const float4 q = b1[d4];
            float dx, dy, dz, dw;
            dx = a.x - p.x; dy = a.y - p.y; dz = a.z - p.z; dw = a.w - p.w;
            a0.x += dx * dx; a0.y += dy * dy; a0.z += dz * dz; a0.w += dw * dw;
            dx = a.x - q.x; dy = a.y - q.y; dz = a.z - q.z; dw = a.w - q.w;
            a1.x += dx * dx; a1.y += dy * dy; a1.z += dz * dz; a1.w += dw * dw;
        }
        const float r0 = sqrtf(a0.x + a0.y + a0.z + a0.w);
        const float r1 = sqrtf(a1.x + a1.y + a1.z + a1.w);
        r_row[t]       = r0;
        r_row[t + 256] = r1;
        ds[t]       = make_float2(fabsf(ti - T[t]),       (t == i)       ? 0.f : __expf(-r0));
        ds[t + 256] = make_float2(fabsf(ti - T[t + 256]), (t + 256 == i) ? 0.f : __expf(-r1));
    }
    __syncthreads();

    sd[t]       = ds[t];
    sd[t + 256] = ds[t + 256];
    __syncthreads();

    // ---- phase 2a: bitonic sort sd[] by key .x ascending (values .y ride along) ----
    for (int k = 2; k <= TWO_N; k <<= 1) {
        for (int jj = k >> 1; jj > 0; jj >>= 1) {
            #pragma unroll
            for (int w = 0; w < 2; ++w) {
                const int e = t + w * 256;
                const int partner = e ^ jj;
                if (partner > e) {                 // exactly one owner per pair
                    const float2 x = sd[e];
                    const float2 y = sd[partner];
                    const bool up = ((e & k) == 0);
                    if (up ? (x.x > y.x) : (x.x < y.x)) {
                        sd[e] = y;
                        sd[partner] = x;
                    }
                }
            }
            __syncthreads();
        }
    }

    // ---- phase 2b: inclusive suffix sum of sorted s ----
    suf[t]       = sd[t].y;
    suf[t + 256] = sd[t + 256].y;
    __syncthreads();
    for (int off = 1; off < TWO_N; off <<= 1) {
        const float v0 = (t + off < TWO_N)       ? suf[t + off]       : 0.f;
        const float v1 = (t + 256 + off < TWO_N) ? suf[t + 256 + off] : 0.f;
        __syncthreads();
        suf[t]       += v0;
        suf[t + 256] += v1;
        __syncthreads();
    }

    // ---- phase 2c: per-k lower_bound -> denom -> loss term ----
    float local = 0.f;
    #pragma unroll
    for (int w = 0; w < 2; ++w) {
        const int k = t + w * 256;
        if (k == i) continue;
        const float th = ds[k].x;
        int pos = 0;                               // count of elements with d < th
        #pragma unroll
        for (int step = 256; step >= 1; step >>= 1) {
            const int np = pos + step;
            if (np <= TWO_N && sd[np - 1].x < th) pos = np;
        }
        const float denom = (pos < TWO_N) ? suf[pos] : 0.f;  // pos<=511 since th is in sd
        local += -r_row[k] - logf(denom);
    }

    // ---- phase 3: block reduction (double) ----
    red[t] = (double)local;
    __syncthreads();
    for (int off = NT / 2; off > 0; off >>= 1) {
        if (t < off) red[t] += red[t + off];
        __syncthreads();
    }
    if (t == 0) block_sums[i] = red[0];
}

__global__ __launch_bounds__(TWO_N) void supcr_finalize(
    const double* __restrict__ block_sums, float* __restrict__ out)
{
    __shared__ double red[TWO_N];
    const int t = threadIdx.x;
    red[t] = block_sums[t];
    __syncthreads();
    for (int off = TWO_N / 2; off > 0; off >>= 1) {
        if (t < off) red[t] += red[t + off];
        __syncthreads();
    }
    if (t == 0)
        out[0] = (float)(-red[0] / (double)((long long)TWO_N * (TWO_N - 1)));
}

extern "C" void kernel_launch(void* const* d_in, const int* in_sizes, int n_in,
                              void* d_out, int out_size, void* d_ws, size_t ws_size,
                              hipStream_t stream) {
    (void)in_sizes; (void)n_in; (void)out_size; (void)ws_size;
    const float* E = (const float*)d_in[0];   // embeddings [512,256] fp32
    const float* T = (const float*)d_in[1];   // targets    [512]     fp32
    float* out = (float*)d_out;
    double* block_sums = (double*)d_ws;       // 512 doubles = 4 KB of ws

    supcr_main<<<TWO_N, NT, 0, stream>>>(E, T, block_sums);
    supcr_finalize<<<1, TWO_N, 0, stream>>>(block_sums, out);
}

// Round 3
// 78.154 us; speedup vs baseline: 1.2956x; 1.2883x over previous
//
#include <hip/hip_runtime.h>
#include <math.h>

#define TWO_N 512
#define DM    256
#define NT    256

// ws layout (bytes):
//   R     : [512*512] float  @ 0          (1 MB)
//   tsort : [512] float      @ 1048576
//   perm  : [512] int        @ 1050624
//   inv   : [512] int        @ 1052672
//   bsums : [512] double     @ 1054720    (8-byte aligned)
#define OFF_TSORT 1048576
#define OFF_PERM  1050624
#define OFF_INV   1052672
#define OFF_BSUM  1054720

#define ACC4(acc, A, B) { float _d;                      \
    _d = (A).x - (B).x; acc += _d * _d;                  \
    _d = (A).y - (B).y; acc += _d * _d;                  \
    _d = (A).z - (B).z; acc += _d * _d;                  \
    _d = (A).w - (B).w; acc += _d * _d; }

// Blocks 0..255: 32x32 distance tiles (squared-diff "GEMM"), coalesced.
// Block 256: bitonic sort of targets -> tsort/perm/inv.
__global__ __launch_bounds__(NT) void supcr_dist_sort(
    const float* __restrict__ E, const float* __restrict__ T,
    float* __restrict__ R, float* __restrict__ tsort,
    int* __restrict__ perm, int* __restrict__ inv)
{
    const int bid = blockIdx.x;
    const int t   = threadIdx.x;

    if (bid < 256) {
        // LDS rows padded to 65 float4 (260 floats): tx-strided reads land on
        // distinct-ish banks (2-way worst case = free).
        __shared__ float4 As4[32 * 65];
        __shared__ float4 Bs4[32 * 65];
        const int it = bid >> 4, jt = bid & 15;
        const float4* __restrict__ E4 = reinterpret_cast<const float4*>(E);

        for (int idx = t; idx < 32 * 64; idx += NT) {    // coalesced staging
            const int row = idx >> 6, c4 = idx & 63;
            As4[row * 65 + c4] = E4[(it * 32 + row) * 64 + c4];
            Bs4[row * 65 + c4] = E4[(jt * 32 + row) * 64 + c4];
        }
        __syncthreads();

        const int ty = t >> 4, tx = t & 15;
        float a00 = 0.f, a01 = 0.f, a10 = 0.f, a11 = 0.f;
        #pragma unroll 8
        for (int k4 = 0; k4 < 64; ++k4) {
            const float4 a0 = As4[ty * 65 + k4];
            const float4 a1 = As4[(ty + 16) * 65 + k4];
            const float4 b0 = Bs4[tx * 65 + k4];
            const float4 b1 = Bs4[(tx + 16) * 65 + k4];
            ACC4(a00, a0, b0); ACC4(a01, a0, b1);
            ACC4(a10, a1, b0); ACC4(a11, a1, b1);
        }
        const int r0 = it * 32 + ty, r1 = r0 + 16;
        const int c0 = jt * 32 + tx, c1 = c0 + 16;
        R[r0 * TWO_N + c0] = sqrtf(a00);
        R[r0 * TWO_N + c1] = sqrtf(a01);
        R[r1 * TWO_N + c0] = sqrtf(a10);
        R[r1 * TWO_N + c1] = sqrtf(a11);
    } else {
        // single-block bitonic sort of 512 (target, index) pairs
        __shared__ float key[TWO_N];
        __shared__ int   pay[TWO_N];
        key[t] = T[t]; key[t + 256] = T[t + 256];
        pay[t] = t;    pay[t + 256] = t + 256;
        __syncthreads();
        for (int kk = 2; kk <= TWO_N; kk <<= 1) {
            for (int j = kk >> 1; j > 0; j >>= 1) {
                #pragma unroll
                for (int w = 0; w < 2; ++w) {
                    const int e = t + w * 256;
                    const int p = e ^ j;
                    if (p > e) {
                        const float a = key[e], b = key[p];
                        const int  pa = pay[e], pb = pay[p];
                        const bool up = ((e & kk) == 0);
                        if (up ? (a > b) : (a < b)) {
                            key[e] = b; key[p] = a;
                            pay[e] = pb; pay[p] = pa;
                        }
                    }
                }
                __syncthreads();
            }
        }
        tsort[t] = key[t];           tsort[t + 256] = key[t + 256];
        perm[t]  = pay[t];           perm[t + 256]  = pay[t + 256];
        inv[pay[t]] = t;             inv[pay[t + 256]] = t + 256;
    }
}

// One block per row i: prefix-sum of s~ in t-sorted order, then per k the
// denom = S_tot - sum over the contiguous interval {d < theta}.
__global__ __launch_bounds__(NT) void supcr_rows(
    const float* __restrict__ T, const float* __restrict__ R,
    const float* __restrict__ tsort, const int* __restrict__ perm,
    const int* __restrict__ inv, double* __restrict__ bsums)
{
    const int i = blockIdx.x;
    const int t = threadIdx.x;

    __shared__ float  ts[TWO_N];
    __shared__ float  P[TWO_N];     // becomes inclusive prefix sums
    __shared__ double red[NT];

    const float ti = T[i];

    #pragma unroll
    for (int w = 0; w < 2; ++w) {
        const int m = t + w * 256;
        ts[m] = tsort[m];
        const int pj = perm[m];
        P[m] = (pj == i) ? 0.f : __expf(-R[(size_t)i * TWO_N + pj]);
    }
    __syncthreads();

    // inclusive prefix sum (Hillis-Steele), 2 elements/thread
    for (int off = 1; off < TWO_N; off <<= 1) {
        const float v0 = (t >= off)       ? P[t - off]       : 0.f;
        const float v1 = (t + 256 >= off) ? P[t + 256 - off] : 0.f;
        __syncthreads();
        P[t]       += v0;
        P[t + 256] += v1;
        __syncthreads();
    }

    const float Stot = P[TWO_N - 1];
    const int   mi   = inv[i];       // sorted position of t_i

    float local = 0.f;
    #pragma unroll
    for (int w = 0; w < 2; ++w) {
        const int k = t + w * 256;
        if (k == i) continue;
        const float theta = fabsf(ti - T[k]);
        const float rik   = R[(size_t)i * TWO_N + k];

        // left arm [0, mi]: d(m)=fabsf(ti-ts[m]) non-increasing.
        // count leading elements with d >= theta (monotone prefix).
        const int nl = mi + 1;
        int pos = 0;
        #pragma unroll
        for (int step = 512; step >= 1; step >>= 1) {
            const int np = pos + step;
            if (np <= nl && fabsf(ti - ts[np - 1]) >= theta) pos = np;
        }
        const int cl = nl - pos;                 // suffix with d < theta

        // right arm [mi, 511]: d non-decreasing. count leading d < theta.
        const int nr = TWO_N - mi;
        int pr = 0;
        #pragma unroll
        for (int step = 512; step >= 1; step >>= 1) {
            const int np = pr + step;
            if (np <= nr && fabsf(ti - ts[mi + np - 1]) < theta) pr = np;
        }
        const int cr = pr;

        // interval with d < theta: [mi-cl+1, mi+cr-1]
        float inner = 0.f;
        const int L  = mi - cl + 1;
        const int Rr = mi + cr - 1;
        if (Rr >= L) inner = P[Rr] - ((L > 0) ? P[L - 1] : 0.f);
        const float denom = Stot - inner;        // = sum over {d >= theta, j != i}
        local += -rik - logf(denom);
    }

    red[t] = (double)local;
    __syncthreads();
    for (int off = NT / 2; off > 0; off >>= 1) {
        if (t < off) red[t] += red[t + off];
        __syncthreads();
    }
    if (t == 0) bsums[i] = red[0];
}

__global__ __launch_bounds__(TWO_N) void supcr_finalize(
    const double* __restrict__ bsums, float* __restrict__ out)
{
    __shared__ double red[TWO_N];
    const int t = threadIdx.x;
    red[t] = bsums[t];
    __syncthreads();
    for (int off = TWO_N / 2; off > 0; off >>= 1) {
        if (t < off) red[t] += red[t + off];
        __syncthreads();
    }
    if (t == 0)
        out[0] = (float)(-red[0] / (double)((long long)TWO_N * (TWO_N - 1)));
}

extern "C" void kernel_launch(void* const* d_in, const int* in_sizes, int n_in,
                              void* d_out, int out_size, void* d_ws, size_t ws_size,
                              hipStream_t stream) {
    (void)in_sizes; (void)n_in; (void)out_size; (void)ws_size;
    const float* E = (const float*)d_in[0];   // [512,256] fp32
    const float* T = (const float*)d_in[1];   // [512]     fp32
    float* out = (float*)d_out;

    char* ws = (char*)d_ws;
    float*  R      = (float*)(ws);
    float*  tsortp = (float*)(ws + OFF_TSORT);
    int*    permp  = (int*)(ws + OFF_PERM);
    int*    invp   = (int*)(ws + OFF_INV);
    double* bsums  = (double*)(ws + OFF_BSUM);

    supcr_dist_sort<<<257, NT, 0, stream>>>(E, T, R, tsortp, permp, invp);
    supcr_rows<<<TWO_N, NT, 0, stream>>>(T, R, tsortp, permp, invp, bsums);
    supcr_finalize<<<1, TWO_N, 0, stream>>>(bsums, out);
}